// Round 6
// baseline (961.404 us; speedup 1.0000x reference)
//
#include <hip/hip_runtime.h>
#include <hip/hip_bf16.h>

// Fused 2-layer tanh-RNN + FC + sigmoid. One block per batch row, 8 waves
// (512 thr, 2 waves/SIMD), wave owns 32 output cols.
// Round-6:
//  * Split-bf16 hidden state (hi+lo, ~16-bit mantissa) to kill the amplified
//    recurrent quantization error (rounds 2-5 sat at the accuracy threshold).
//    Recurrence: hi in A-row 0, lo in A-row 1 of the same MFMA (M was unused)
//    -> preact = acc[0] + acc[1], ZERO extra MFMAs. Phases A/C: 2-pass hi/lo.
//  * No pack kernel / d_ws. Whh0+Whh1 in 128 AGPRs (asm "a"); Wih0 = 4
//    permanent VGPR frags; Wih1 streamed from L2 per chunk (f32 ldfrag).
//  * LDS ~58KB, padded strides (264 ushort / 260 float) for bank spread.

#define BB  256
#define SS  512
#define DIN 64
#define HH  256
#define TT  16
#define NC  (SS/TT)
#define STH 264   // ushort stride of one h row (528B = 33*16B, bank-skewed)

typedef __attribute__((ext_vector_type(8))) short short8;
typedef __attribute__((ext_vector_type(4))) float f32x4;

#define MFMA(a, b, c) __builtin_amdgcn_mfma_f32_16x16x32_bf16((a), (b), (c), 0, 0, 0)

// acc += A * B with B pinned in AGPRs
__device__ __forceinline__ void mfma_a(f32x4& acc, short8 a, short8 b) {
    asm("v_mfma_f32_16x16x32_bf16 %0, %1, %2, %0" : "+v"(acc) : "v"(a), "a"(b));
}
// acc = A * B + C (C = hoisted zero register)
__device__ __forceinline__ f32x4 mfma_az(short8 a, short8 b, f32x4 c) {
    f32x4 d;
    asm("v_mfma_f32_16x16x32_bf16 %0, %1, %2, %3"
        : "=&v"(d) : "v"(a), "a"(b), "v"(c));
    return d;
}

__device__ __forceinline__ short bf16r(float f) {
    union { float f; unsigned u; } v; v.f = f;
    unsigned r = v.u + 0x7FFFu + ((v.u >> 16) & 1u);   // RTNE
    return (short)(r >> 16);
}

__device__ __forceinline__ float bf2f(ushort h) {
    union { unsigned u; float f; } v; v.u = ((unsigned)h) << 16;
    return v.f;
}

__device__ __forceinline__ short8 ldfrag(const float* __restrict__ p) {
    f32x4 a = *(const f32x4*)p;
    f32x4 b = *(const f32x4*)(p + 4);
    short8 v;
#pragma unroll
    for (int j = 0; j < 4; ++j) { v[j] = bf16r(a[j]); v[4 + j] = bf16r(b[j]); }
    return v;
}

// tanh(x) = 1 - 2/(exp2(2x/ln2)+1)
__device__ __forceinline__ float tanh_fast(float x) {
    float e = __builtin_amdgcn_exp2f(x * 2.885390081777927f);
    return 1.0f - 2.0f * __builtin_amdgcn_rcpf(e + 1.0f);
}

__global__ __launch_bounds__(512, 2)
void rnn_fused_kernel(const float* __restrict__ x,
                      const float* __restrict__ Wih0, const float* __restrict__ Whh0,
                      const float* __restrict__ bih0, const float* __restrict__ bhh0,
                      const float* __restrict__ Wih1, const float* __restrict__ Whh1,
                      const float* __restrict__ bih1, const float* __restrict__ bhh1,
                      const float* __restrict__ Wfc,  const float* __restrict__ bfc,
                      float* __restrict__ out)
{
    const int b    = blockIdx.x;
    const int tid  = threadIdx.x;
    const int wid  = tid >> 6;        // wave 0..7, owns cols [32*wid, 32*wid+32)
    const int lane = tid & 63;
    const int c15  = lane & 15;       // MFMA A-row / B-col / D-col index
    const int kg   = lane >> 4;       // k-group
    const int mlow = lane & 1;        // 0 -> hi row, 1 -> lo row (A rows 0/1)
    const int cb0  = 32 * wid + c15;  // output col of n=0 tile; n=1 adds 16

    __shared__ alignas(16) ushort xs[TT][2][72];        // x hi/lo    (4.6 KB)
    __shared__ alignas(16) float  xp[TT][260];          // xp + bias0 (16.6 KB)
    __shared__ alignas(16) float  uch[TT][260];         // u + bias1  (16.6 KB)
    __shared__ alignas(16) ushort h0s[TT + 1][2][STH];  // h0 hi/lo hist (18 KB)
    __shared__ alignas(16) ushort h1s[2][2][STH];       // h1 hi/lo pp  (2.1 KB)

    // zero carry-in state (hi and lo planes)
    for (int i = tid; i < 2 * STH; i += 512) {
        (&h0s[0][0][0])[i] = 0;
        (&h1s[1][0][0])[i] = 0;
    }

    // ---- permanent weights ----
    // B-frag for col = cb0+16n, k = 32kf + 8kg + j.
    float  bias0[2], bias1[2];
    short8 wih0f[2][2];                 // VGPR-permanent (16 regs)
    short8 whh0a[8][2], whh1a[8][2];    // AGPR via asm "a" (128 regs)
#pragma unroll
    for (int n = 0; n < 2; ++n) {
        const int col = cb0 + 16 * n;
        bias0[n] = bih0[col] + bhh0[col];
        bias1[n] = bih1[col] + bhh1[col];
#pragma unroll
        for (int kf = 0; kf < 2; ++kf)
            wih0f[kf][n] = ldfrag(Wih0 + (size_t)col * DIN + 32 * kf + 8 * kg);
#pragma unroll
        for (int kf = 0; kf < 8; ++kf) {
            whh0a[kf][n] = ldfrag(Whh0 + (size_t)col * HH + 32 * kf + 8 * kg);
            whh1a[kf][n] = ldfrag(Whh1 + (size_t)col * HH + 32 * kf + 8 * kg);
        }
    }

    const f32x4 vz = {0.f, 0.f, 0.f, 0.f};
    const float* xb = x + (size_t)b * SS * DIN;
    float xr0 = xb[tid], xr1 = xb[tid + 512];
    __syncthreads();   // zero-init visible

    for (int c = 0; c < NC; ++c) {
        // ---- phase A: stage x hi/lo; xp = x @ Wih0^T + bias0 (M=16, 2-pass) ----
        {
            const int i0 = tid, i1 = tid + 512;
            ushort h;
            h = (ushort)bf16r(xr0);
            xs[i0 >> 6][0][i0 & 63] = h;
            xs[i0 >> 6][1][i0 & 63] = (ushort)bf16r(xr0 - bf2f(h));
            h = (ushort)bf16r(xr1);
            xs[i1 >> 6][0][i1 & 63] = h;
            xs[i1 >> 6][1][i1 & 63] = (ushort)bf16r(xr1 - bf2f(h));
        }
        if (c + 1 < NC) {
            const float* xsrc = xb + (size_t)(c + 1) * TT * DIN;
            xr0 = xsrc[tid]; xr1 = xsrc[tid + 512];
        }
        __syncthreads();
        {
            f32x4 axp[2] = {vz, vz};
#pragma unroll
            for (int pass = 0; pass < 2; ++pass)
#pragma unroll
                for (int kf = 0; kf < 2; ++kf) {
                    const short8 ax = *(const short8*)(&xs[c15][pass][32 * kf + 8 * kg]);
                    axp[0] = MFMA(ax, wih0f[kf][0], axp[0]);
                    axp[1] = MFMA(ax, wih0f[kf][1], axp[1]);
                }
#pragma unroll
            for (int n = 0; n < 2; ++n)
#pragma unroll
                for (int j = 0; j < 4; ++j)
                    xp[4 * kg + j][cb0 + 16 * n] = axp[n][j] + bias0[n];
        }
        __syncthreads();

        // ---- phase B(c) + D(c-1): both recurrences, hi/lo in A-rows 0/1 ----
        const bool doD = (c > 0);
        for (int r = 0; r < TT; ++r) {
            const int dcur = r & 1, dprv = dcur ^ 1;
            float xpv[2], uv[2] = {0.f, 0.f};
#pragma unroll
            for (int n = 0; n < 2; ++n) xpv[n] = xp[r][cb0 + 16 * n];
            if (doD) {
#pragma unroll
                for (int n = 0; n < 2; ++n) uv[n] = uch[r][cb0 + 16 * n];
            }
            const ushort* h0p = &h0s[r][0][0] + mlow * STH + 8 * kg;
            const ushort* h1p = &h1s[dprv][0][0] + mlow * STH + 8 * kg;
            f32x4 a0[2], a1[2];
            {   // kf = 0: C = hoisted zero
                const short8 ah0 = *(const short8*)(h0p);
                a0[0] = mfma_az(ah0, whh0a[0][0], vz);
                a0[1] = mfma_az(ah0, whh0a[0][1], vz);
                if (doD) {
                    const short8 ah1 = *(const short8*)(h1p);
                    a1[0] = mfma_az(ah1, whh1a[0][0], vz);
                    a1[1] = mfma_az(ah1, whh1a[0][1], vz);
                }
            }
#pragma unroll
            for (int kf = 1; kf < 8; ++kf) {
                const short8 ah0 = *(const short8*)(h0p + 32 * kf);
                mfma_a(a0[0], ah0, whh0a[kf][0]);
                mfma_a(a0[1], ah0, whh0a[kf][1]);
                if (doD) {
                    const short8 ah1 = *(const short8*)(h1p + 32 * kf);
                    mfma_a(a1[0], ah1, whh1a[kf][0]);
                    mfma_a(a1[1], ah1, whh1a[kf][1]);
                }
            }
            // D rows 0 (hi product) and 1 (lo product) live on lanes 0..15,
            // regs 0 and 1. preact = acc[0] + acc[1] (+ xp/u).
            if (lane < 16) {
#pragma unroll
                for (int n = 0; n < 2; ++n) {
                    const int col = 32 * wid + 16 * n + lane;
                    const float h = tanh_fast(a0[n][0] + a0[n][1] + xpv[n]);
                    const ushort hi = (ushort)bf16r(h);
                    h0s[r + 1][0][col] = hi;
                    h0s[r + 1][1][col] = (ushort)bf16r(h - bf2f(hi));
                }
                if (doD) {
#pragma unroll
                    for (int n = 0; n < 2; ++n) {
                        const int col = 32 * wid + 16 * n + lane;
                        const float h = tanh_fast(a1[n][0] + a1[n][1] + uv[n]);
                        const ushort hi = (ushort)bf16r(h);
                        h1s[dcur][0][col] = hi;
                        h1s[dcur][1][col] = (ushort)bf16r(h - bf2f(hi));
                    }
                }
            }
            __syncthreads();
        }

        // ---- phase C: u(c) = h0 @ Wih1^T + bias1 (M=16 timesteps, 2-pass);
        //      Wih1 frags streamed from L2 in two kf-halves (32 reg transient) ----
        {
            f32x4 au[2] = {vz, vz};
#pragma unroll
            for (int half = 0; half < 2; ++half) {
                short8 wf[4][2];
#pragma unroll
                for (int kq = 0; kq < 4; ++kq)
#pragma unroll
                    for (int n = 0; n < 2; ++n)
                        wf[kq][n] = ldfrag(Wih1 + (size_t)(cb0 + 16 * n) * HH +
                                           32 * (4 * half + kq) + 8 * kg);
#pragma unroll
                for (int pass = 0; pass < 2; ++pass)
#pragma unroll
                    for (int kq = 0; kq < 4; ++kq) {
                        const short8 a = *(const short8*)(
                            &h0s[1 + c15][pass][32 * (4 * half + kq) + 8 * kg]);
                        au[0] = MFMA(a, wf[kq][0], au[0]);
                        au[1] = MFMA(a, wf[kq][1], au[1]);
                    }
            }
#pragma unroll
            for (int n = 0; n < 2; ++n)
#pragma unroll
                for (int j = 0; j < 4; ++j)
                    uch[4 * kg + j][cb0 + 16 * n] = au[n][j] + bias1[n];
            // carry h0 (hi+lo planes) into next chunk; row 0 disjoint from
            // the rows 1..16 phase C reads.
            for (int i = tid; i < 2 * STH; i += 512)
                (&h0s[0][0][0])[i] = (&h0s[TT][0][0])[i];
        }
        __syncthreads();
    }

    // ---- drain: layer-1 recurrence for the last chunk ----
    for (int r = 0; r < TT; ++r) {
        const int dcur = r & 1, dprv = dcur ^ 1;
        float uv[2];
#pragma unroll
        for (int n = 0; n < 2; ++n) uv[n] = uch[r][cb0 + 16 * n];
        const ushort* h1p = &h1s[dprv][0][0] + mlow * STH + 8 * kg;
        f32x4 a1[2];
        {
            const short8 ah1 = *(const short8*)(h1p);
            a1[0] = mfma_az(ah1, whh1a[0][0], vz);
            a1[1] = mfma_az(ah1, whh1a[0][1], vz);
        }
#pragma unroll
        for (int kf = 1; kf < 8; ++kf) {
            const short8 ah1 = *(const short8*)(h1p + 32 * kf);
            mfma_a(a1[0], ah1, whh1a[kf][0]);
            mfma_a(a1[1], ah1, whh1a[kf][1]);
        }
        if (lane < 16) {
#pragma unroll
            for (int n = 0; n < 2; ++n) {
                const int col = 32 * wid + 16 * n + lane;
                const float h = tanh_fast(a1[n][0] + a1[n][1] + uv[n]);
                const ushort hi = (ushort)bf16r(h);
                h1s[dcur][0][col] = hi;
                h1s[dcur][1][col] = (ushort)bf16r(h - bf2f(hi));
            }
        }
        __syncthreads();
    }

    // ---- FC + sigmoid on final h1 (r=15 -> parity 1), hi+lo recombined ----
    if (wid == 0) {
        float p = 0.f;
#pragma unroll
        for (int i = 0; i < 4; ++i) {
            const int ii = 4 * lane + i;
            p += (bf2f(h1s[1][0][ii]) + bf2f(h1s[1][1][ii])) * Wfc[ii];
        }
#pragma unroll
        for (int off = 32; off > 0; off >>= 1) p += __shfl_down(p, off);
        if (lane == 0) {
            const float z = p + bfc[0];
            out[b] = 1.f / (1.f + expf(-z));
        }
    }
}

extern "C" void kernel_launch(void* const* d_in, const int* in_sizes, int n_in,
                              void* d_out, int out_size, void* d_ws, size_t ws_size,
                              hipStream_t stream) {
    (void)in_sizes; (void)n_in; (void)d_ws; (void)ws_size; (void)out_size;
    const float* x    = (const float*)d_in[0];
    const float* Wih0 = (const float*)d_in[1];
    const float* Whh0 = (const float*)d_in[2];
    const float* bih0 = (const float*)d_in[3];
    const float* bhh0 = (const float*)d_in[4];
    const float* Wih1 = (const float*)d_in[5];
    const float* Whh1 = (const float*)d_in[6];
    const float* bih1 = (const float*)d_in[7];
    const float* bhh1 = (const float*)d_in[8];
    const float* Wfc  = (const float*)d_in[9];
    const float* bfc  = (const float*)d_in[10];
    float* out = (float*)d_out;

    rnn_fused_kernel<<<dim3(BB), dim3(512), 0, stream>>>(
        x, Wih0, Whh0, bih0, bhh0, Wih1, Whh1, bih1, bhh1, Wfc, bfc, out);
}

// Round 7
// 950.392 us; speedup vs baseline: 1.0116x; 1.0116x over previous
//
#include <hip/hip_runtime.h>
#include <hip/hip_bf16.h>

// Fused 2-layer tanh-RNN + FC + sigmoid. One block per batch row, 8 waves
// (512 thr, 2 waves/SIMD), wave owns 32 output cols.
// Round-7 (vs round-6, which passed at absmax 0.00195 but regressed to 961us):
//  * h hi/lo planes at 576B stride, rows at 1168B: the 8 recurrence-read
//    addresses {plane,kg} land on bank starts {0,4,..,28} -> ZERO ds_read
//    conflicts (r6's 528B plane offset overlapped ranges; conflicts 3.7x'd).
//  * All-64-lane tail: A-rows alternate hi/lo, so D rows {4kg,4kg+1} put
//    (hi+lo) products on EVERY lane group. Lane quadrant = (layer, n-tile);
//    one tanh chain per lane, no shuffles, no lane<16 serialization.
//  * Whh0+Whh1 in 128 AGPRs (asm "a"); Wih0 4 VGPR frags; Wih1 streamed.

#define BB  256
#define SS  512
#define DIN 64
#define HH  256
#define TT  16
#define NC  (SS/TT)
#define HP  288   // ushort plane stride (576B = 144dw = +16 banks)
#define HR  584   // ushort row stride  (1168B = 292dw = +4 banks)

typedef __attribute__((ext_vector_type(8))) short short8;
typedef __attribute__((ext_vector_type(4))) float f32x4;

#define MFMA(a, b, c) __builtin_amdgcn_mfma_f32_16x16x32_bf16((a), (b), (c), 0, 0, 0)

// acc += A * B with B pinned in AGPRs
__device__ __forceinline__ void mfma_a(f32x4& acc, short8 a, short8 b) {
    asm("v_mfma_f32_16x16x32_bf16 %0, %1, %2, %0" : "+v"(acc) : "v"(a), "a"(b));
}
// acc = A * B + C (C = hoisted zero register)
__device__ __forceinline__ f32x4 mfma_az(short8 a, short8 b, f32x4 c) {
    f32x4 d;
    asm("v_mfma_f32_16x16x32_bf16 %0, %1, %2, %3"
        : "=&v"(d) : "v"(a), "a"(b), "v"(c));
    return d;
}

__device__ __forceinline__ short bf16r(float f) {
    union { float f; unsigned u; } v; v.f = f;
    unsigned r = v.u + 0x7FFFu + ((v.u >> 16) & 1u);   // RTNE
    return (short)(r >> 16);
}

__device__ __forceinline__ float bf2f(ushort h) {
    union { unsigned u; float f; } v; v.u = ((unsigned)h) << 16;
    return v.f;
}

__device__ __forceinline__ short8 ldfrag(const float* __restrict__ p) {
    f32x4 a = *(const f32x4*)p;
    f32x4 b = *(const f32x4*)(p + 4);
    short8 v;
#pragma unroll
    for (int j = 0; j < 4; ++j) { v[j] = bf16r(a[j]); v[4 + j] = bf16r(b[j]); }
    return v;
}

// tanh(x) = 1 - 2/(exp2(2x/ln2)+1)
__device__ __forceinline__ float tanh_fast(float x) {
    float e = __builtin_amdgcn_exp2f(x * 2.885390081777927f);
    return 1.0f - 2.0f * __builtin_amdgcn_rcpf(e + 1.0f);
}

__global__ __launch_bounds__(512, 2)
void rnn_fused_kernel(const float* __restrict__ x,
                      const float* __restrict__ Wih0, const float* __restrict__ Whh0,
                      const float* __restrict__ bih0, const float* __restrict__ bhh0,
                      const float* __restrict__ Wih1, const float* __restrict__ Whh1,
                      const float* __restrict__ bih1, const float* __restrict__ bhh1,
                      const float* __restrict__ Wfc,  const float* __restrict__ bfc,
                      float* __restrict__ out)
{
    const int b    = blockIdx.x;
    const int tid  = threadIdx.x;
    const int wid  = tid >> 6;        // wave 0..7, owns cols [32*wid, 32*wid+32)
    const int lane = tid & 63;
    const int c15  = lane & 15;
    const int kg   = lane >> 4;
    const int mlow = lane & 1;        // A-row parity -> hi(0)/lo(1) plane
    const int cb0  = 32 * wid + c15;

    __shared__ alignas(16) ushort xs[TT][2][72];      // x hi/lo       (4.6 KB)
    __shared__ alignas(16) float  xp[TT][260];        // xp + bias0   (16.6 KB)
    __shared__ alignas(16) float  uch[TT][260];       // u + bias1    (16.6 KB)
    __shared__ alignas(16) ushort h0f[(TT + 1) * HR]; // h0 hist      (19.9 KB)
    __shared__ alignas(16) ushort h1f[2 * HR];        // h1 ping-pong  (2.3 KB)

    // zero carry-in rows (both planes; pads too)
    for (int i = tid; i < HR; i += 512) { h0f[i] = 0; h1f[HR + i] = 0; }

    // ---- permanent weights (B-frag: col = cb0+16n, k = 32kf + 8kg + j) ----
    float  bias0[2], bias1[2];
    short8 wih0f[2][2];                 // VGPR-permanent
    short8 whh0a[8][2], whh1a[8][2];    // AGPR via asm "a" (128 regs)
#pragma unroll
    for (int n = 0; n < 2; ++n) {
        const int col = cb0 + 16 * n;
        bias0[n] = bih0[col] + bhh0[col];
        bias1[n] = bih1[col] + bhh1[col];
#pragma unroll
        for (int kf = 0; kf < 2; ++kf)
            wih0f[kf][n] = ldfrag(Wih0 + (size_t)col * DIN + 32 * kf + 8 * kg);
#pragma unroll
        for (int kf = 0; kf < 8; ++kf) {
            whh0a[kf][n] = ldfrag(Whh0 + (size_t)col * HH + 32 * kf + 8 * kg);
            whh1a[kf][n] = ldfrag(Whh1 + (size_t)col * HH + 32 * kf + 8 * kg);
        }
    }

    const f32x4 vz = {0.f, 0.f, 0.f, 0.f};
    const float* xb = x + (size_t)b * SS * DIN;
    float xr0 = xb[tid], xr1 = xb[tid + 512];
    __syncthreads();   // zero-init visible

    for (int c = 0; c < NC; ++c) {
        // ---- phase A: stage x hi/lo; xp = x @ Wih0^T + bias0 (M=16, 2-pass) ----
        {
            const int i0 = tid, i1 = tid + 512;
            ushort h;
            h = (ushort)bf16r(xr0);
            xs[i0 >> 6][0][i0 & 63] = h;
            xs[i0 >> 6][1][i0 & 63] = (ushort)bf16r(xr0 - bf2f(h));
            h = (ushort)bf16r(xr1);
            xs[i1 >> 6][0][i1 & 63] = h;
            xs[i1 >> 6][1][i1 & 63] = (ushort)bf16r(xr1 - bf2f(h));
        }
        if (c + 1 < NC) {
            const float* xsrc = xb + (size_t)(c + 1) * TT * DIN;
            xr0 = xsrc[tid]; xr1 = xsrc[tid + 512];
        }
        __syncthreads();
        {
            f32x4 axp[2] = {vz, vz};
#pragma unroll
            for (int pass = 0; pass < 2; ++pass)
#pragma unroll
                for (int kf = 0; kf < 2; ++kf) {
                    const short8 ax = *(const short8*)(&xs[c15][pass][32 * kf + 8 * kg]);
                    axp[0] = MFMA(ax, wih0f[kf][0], axp[0]);
                    axp[1] = MFMA(ax, wih0f[kf][1], axp[1]);
                }
#pragma unroll
            for (int n = 0; n < 2; ++n)
#pragma unroll
                for (int j = 0; j < 4; ++j)
                    xp[4 * kg + j][cb0 + 16 * n] = axp[n][j] + bias0[n];
        }
        __syncthreads();

        // ---- phase B(c) + D(c-1): both recurrences; hi/lo in alternating A-rows ----
        const bool doD = (c > 0);
        for (int r = 0; r < TT; ++r) {
            const int dcur = r & 1, dprv = dcur ^ 1;
            const int ccol = 32 * wid + (lane & 31);
            const float xv  = xp[r][ccol];    // layer-0 addend (lanes 0..31)
            const float uvv = uch[r][ccol];   // layer-1 addend (lanes 32..63)

            const ushort* h0p = &h0f[r * HR + mlow * HP + 8 * kg];
            const ushort* h1p = &h1f[dprv * HR + mlow * HP + 8 * kg];
            f32x4 a0[2], a1[2] = {vz, vz};
            {   // kf = 0: C = hoisted zero
                const short8 ah0 = *(const short8*)(h0p);
                a0[0] = mfma_az(ah0, whh0a[0][0], vz);
                a0[1] = mfma_az(ah0, whh0a[0][1], vz);
                if (doD) {
                    const short8 ah1 = *(const short8*)(h1p);
                    a1[0] = mfma_az(ah1, whh1a[0][0], vz);
                    a1[1] = mfma_az(ah1, whh1a[0][1], vz);
                }
            }
#pragma unroll
            for (int kf = 1; kf < 8; ++kf) {
                const short8 ah0 = *(const short8*)(h0p + 32 * kf);
                mfma_a(a0[0], ah0, whh0a[kf][0]);
                mfma_a(a0[1], ah0, whh0a[kf][1]);
                if (doD) {
                    const short8 ah1 = *(const short8*)(h1p + 32 * kf);
                    mfma_a(a1[0], ah1, whh1a[kf][0]);
                    mfma_a(a1[1], ah1, whh1a[kf][1]);
                }
            }
            // all-64-lane tail: D rows {4kg,4kg+1} = {hi,lo} products on every
            // lane group; quadrant -> (layer = lane>=32, n = (lane>>4)&1).
            {
                const int qn = (lane >> 4) & 1;
                const float s0 = a0[qn][0] + a0[qn][1];
                const float s1 = a1[qn][0] + a1[qn][1];
                const float h  = tanh_fast(((lane < 32) ? s0 : s1) +
                                           ((lane < 32) ? xv : uvv));
                const ushort hi = (ushort)bf16r(h);
                const ushort lo = (ushort)bf16r(h - bf2f(hi));
                ushort* dst = (lane < 32) ? &h0f[(r + 1) * HR] : &h1f[dcur * HR];
                if (doD || lane < 32) {
                    dst[ccol]      = hi;
                    dst[HP + ccol] = lo;
                }
            }
            __syncthreads();
        }

        // ---- phase C: u(c) = h0 @ Wih1^T + bias1 (M=16 timesteps, 2-pass);
        //      Wih1 frags streamed from L2 in two kf-halves ----
        {
            f32x4 au[2] = {vz, vz};
#pragma unroll
            for (int half = 0; half < 2; ++half) {
                short8 wf[4][2];
#pragma unroll
                for (int kq = 0; kq < 4; ++kq)
#pragma unroll
                    for (int n = 0; n < 2; ++n)
                        wf[kq][n] = ldfrag(Wih1 + (size_t)(cb0 + 16 * n) * HH +
                                           32 * (4 * half + kq) + 8 * kg);
#pragma unroll
                for (int pass = 0; pass < 2; ++pass)
#pragma unroll
                    for (int kq = 0; kq < 4; ++kq) {
                        const short8 a = *(const short8*)(
                            &h0f[(1 + c15) * HR + pass * HP + 32 * (4 * half + kq) + 8 * kg]);
                        au[0] = MFMA(a, wf[kq][0], au[0]);
                        au[1] = MFMA(a, wf[kq][1], au[1]);
                    }
            }
#pragma unroll
            for (int n = 0; n < 2; ++n)
#pragma unroll
                for (int j = 0; j < 4; ++j)
                    uch[4 * kg + j][cb0 + 16 * n] = au[n][j] + bias1[n];
            // carry h0 row 16 -> row 0 (row 0 disjoint from phase-C rows 1..16)
            for (int i = tid; i < HR; i += 512) h0f[i] = h0f[TT * HR + i];
        }
        __syncthreads();
    }

    // ---- drain: layer-1 recurrence for the last chunk ----
    for (int r = 0; r < TT; ++r) {
        const int dcur = r & 1, dprv = dcur ^ 1;
        const int ccol = 32 * wid + (lane & 31);
        const float uvv = uch[r][ccol];
        const ushort* h1p = &h1f[dprv * HR + mlow * HP + 8 * kg];
        f32x4 a1[2];
        {
            const short8 ah1 = *(const short8*)(h1p);
            a1[0] = mfma_az(ah1, whh1a[0][0], vz);
            a1[1] = mfma_az(ah1, whh1a[0][1], vz);
        }
#pragma unroll
        for (int kf = 1; kf < 8; ++kf) {
            const short8 ah1 = *(const short8*)(h1p + 32 * kf);
            mfma_a(a1[0], ah1, whh1a[kf][0]);
            mfma_a(a1[1], ah1, whh1a[kf][1]);
        }
        {
            const int qn = (lane >> 4) & 1;
            const float h = tanh_fast(a1[qn][0] + a1[qn][1] + uvv);
            const ushort hi = (ushort)bf16r(h);
            const ushort lo = (ushort)bf16r(h - bf2f(hi));
            if (lane >= 32) {           // quadrants 2-3 own the h1 write
                h1f[dcur * HR + ccol]      = hi;
                h1f[dcur * HR + HP + ccol] = lo;
            }
        }
        __syncthreads();
    }

    // ---- FC + sigmoid on final h1 (r=15 -> parity 1), hi+lo recombined ----
    if (wid == 0) {
        float p = 0.f;
#pragma unroll
        for (int i = 0; i < 4; ++i) {
            const int ii = 4 * lane + i;
            p += (bf2f(h1f[HR + ii]) + bf2f(h1f[HR + HP + ii])) * Wfc[ii];
        }
#pragma unroll
        for (int off = 32; off > 0; off >>= 1) p += __shfl_down(p, off);
        if (lane == 0) {
            const float z = p + bfc[0];
            out[b] = 1.f / (1.f + expf(-z));
        }
    }
}

extern "C" void kernel_launch(void* const* d_in, const int* in_sizes, int n_in,
                              void* d_out, int out_size, void* d_ws, size_t ws_size,
                              hipStream_t stream) {
    (void)in_sizes; (void)n_in; (void)d_ws; (void)ws_size; (void)out_size;
    const float* x    = (const float*)d_in[0];
    const float* Wih0 = (const float*)d_in[1];
    const float* Whh0 = (const float*)d_in[2];
    const float* bih0 = (const float*)d_in[3];
    const float* bhh0 = (const float*)d_in[4];
    const float* Wih1 = (const float*)d_in[5];
    const float* Whh1 = (const float*)d_in[6];
    const float* bih1 = (const float*)d_in[7];
    const float* bhh1 = (const float*)d_in[8];
    const float* Wfc  = (const float*)d_in[9];
    const float* bfc  = (const float*)d_in[10];
    float* out = (float*)d_out;

    rnn_fused_kernel<<<dim3(BB), dim3(512), 0, stream>>>(
        x, Wih0, Whh0, bih0, bhh0, Wih1, Whh1, bih1, bhh1, Wfc, bfc, out);
}

// Round 8
// 865.296 us; speedup vs baseline: 1.1111x; 1.0983x over previous
//
#include <hip/hip_runtime.h>
#include <hip/hip_bf16.h>

// Fused 2-layer tanh-RNN + FC + sigmoid. One block per batch row, 8 waves
// (512 thr, 2 waves/SIMD), wave owns 32 output cols.
// Round-8 (vs round-7, 950us):
//  * Rule-#20 fix: r7's tail indexed accumulator arrays with RUNTIME qn
//    (a0[qn][0]) -> compiler demoted accs to scratch (WRITE_SIZE 8.2MB,
//    VALUBusy 40%). Now: compile-time reads + v_cndmask value-selects.
//  * One addend LDS read per lane (pointer-select xp/uch).
//  * Phase C streams Wih1 2 frags at a time (transient 8 regs, not 32).
//  * Keeps r7's zero-conflict strides (HP=288, HR=584) and all-lane tail.

#define BB  256
#define SS  512
#define DIN 64
#define HH  256
#define TT  16
#define NC  (SS/TT)
#define HP  288   // ushort plane stride (576B = +16 banks)
#define HR  584   // ushort row stride  (1168B = +4 banks)

typedef __attribute__((ext_vector_type(8))) short short8;
typedef __attribute__((ext_vector_type(4))) float f32x4;

#define MFMA(a, b, c) __builtin_amdgcn_mfma_f32_16x16x32_bf16((a), (b), (c), 0, 0, 0)

// acc += A * B with B pinned in AGPRs
__device__ __forceinline__ void mfma_a(f32x4& acc, short8 a, short8 b) {
    asm("v_mfma_f32_16x16x32_bf16 %0, %1, %2, %0" : "+v"(acc) : "v"(a), "a"(b));
}
// acc = A * B + C (C = hoisted zero register)
__device__ __forceinline__ f32x4 mfma_az(short8 a, short8 b, f32x4 c) {
    f32x4 d;
    asm("v_mfma_f32_16x16x32_bf16 %0, %1, %2, %3"
        : "=&v"(d) : "v"(a), "a"(b), "v"(c));
    return d;
}

__device__ __forceinline__ short bf16r(float f) {
    union { float f; unsigned u; } v; v.f = f;
    unsigned r = v.u + 0x7FFFu + ((v.u >> 16) & 1u);   // RTNE
    return (short)(r >> 16);
}

__device__ __forceinline__ float bf2f(ushort h) {
    union { unsigned u; float f; } v; v.u = ((unsigned)h) << 16;
    return v.f;
}

__device__ __forceinline__ short8 ldfrag(const float* __restrict__ p) {
    f32x4 a = *(const f32x4*)p;
    f32x4 b = *(const f32x4*)(p + 4);
    short8 v;
#pragma unroll
    for (int j = 0; j < 4; ++j) { v[j] = bf16r(a[j]); v[4 + j] = bf16r(b[j]); }
    return v;
}

// tanh(x) = 1 - 2/(exp2(2x/ln2)+1)
__device__ __forceinline__ float tanh_fast(float x) {
    float e = __builtin_amdgcn_exp2f(x * 2.885390081777927f);
    return 1.0f - 2.0f * __builtin_amdgcn_rcpf(e + 1.0f);
}

__global__ __launch_bounds__(512, 2)
void rnn_fused_kernel(const float* __restrict__ x,
                      const float* __restrict__ Wih0, const float* __restrict__ Whh0,
                      const float* __restrict__ bih0, const float* __restrict__ bhh0,
                      const float* __restrict__ Wih1, const float* __restrict__ Whh1,
                      const float* __restrict__ bih1, const float* __restrict__ bhh1,
                      const float* __restrict__ Wfc,  const float* __restrict__ bfc,
                      float* __restrict__ out)
{
    const int b    = blockIdx.x;
    const int tid  = threadIdx.x;
    const int wid  = tid >> 6;        // wave 0..7, owns cols [32*wid, 32*wid+32)
    const int lane = tid & 63;
    const int c15  = lane & 15;
    const int kg   = lane >> 4;
    const int mlow = lane & 1;        // A-row parity -> hi(0)/lo(1) plane
    const int cb0  = 32 * wid + c15;

    __shared__ alignas(16) ushort xs[TT][2][72];      // x hi/lo       (4.6 KB)
    __shared__ alignas(16) float  xp[TT][260];        // xp + bias0   (16.6 KB)
    __shared__ alignas(16) float  uch[TT][260];       // u + bias1    (16.6 KB)
    __shared__ alignas(16) ushort h0f[(TT + 1) * HR]; // h0 hist      (19.9 KB)
    __shared__ alignas(16) ushort h1f[2 * HR];        // h1 ping-pong  (2.3 KB)

    // zero carry-in rows (both planes; pads too)
    for (int i = tid; i < HR; i += 512) { h0f[i] = 0; h1f[HR + i] = 0; }

    // ---- permanent weights (B-frag: col = cb0+16n, k = 32kf + 8kg + j) ----
    float  bias0[2], bias1[2];
    short8 wih0f[2][2];                 // VGPR-permanent
    short8 whh0a[8][2], whh1a[8][2];    // AGPR via asm "a" (128 regs)
#pragma unroll
    for (int n = 0; n < 2; ++n) {
        const int col = cb0 + 16 * n;
        bias0[n] = bih0[col] + bhh0[col];
        bias1[n] = bih1[col] + bhh1[col];
#pragma unroll
        for (int kf = 0; kf < 2; ++kf)
            wih0f[kf][n] = ldfrag(Wih0 + (size_t)col * DIN + 32 * kf + 8 * kg);
#pragma unroll
        for (int kf = 0; kf < 8; ++kf) {
            whh0a[kf][n] = ldfrag(Whh0 + (size_t)col * HH + 32 * kf + 8 * kg);
            whh1a[kf][n] = ldfrag(Whh1 + (size_t)col * HH + 32 * kf + 8 * kg);
        }
    }

    const f32x4 vz = {0.f, 0.f, 0.f, 0.f};
    const float* xb = x + (size_t)b * SS * DIN;
    float xr0 = xb[tid], xr1 = xb[tid + 512];
    __syncthreads();   // zero-init visible

    for (int c = 0; c < NC; ++c) {
        // ---- phase A: stage x hi/lo; xp = x @ Wih0^T + bias0 (M=16, 2-pass) ----
        {
            const int i0 = tid, i1 = tid + 512;
            ushort h;
            h = (ushort)bf16r(xr0);
            xs[i0 >> 6][0][i0 & 63] = h;
            xs[i0 >> 6][1][i0 & 63] = (ushort)bf16r(xr0 - bf2f(h));
            h = (ushort)bf16r(xr1);
            xs[i1 >> 6][0][i1 & 63] = h;
            xs[i1 >> 6][1][i1 & 63] = (ushort)bf16r(xr1 - bf2f(h));
        }
        if (c + 1 < NC) {
            const float* xsrc = xb + (size_t)(c + 1) * TT * DIN;
            xr0 = xsrc[tid]; xr1 = xsrc[tid + 512];
        }
        __syncthreads();
        {
            f32x4 axp[2] = {vz, vz};
#pragma unroll
            for (int pass = 0; pass < 2; ++pass)
#pragma unroll
                for (int kf = 0; kf < 2; ++kf) {
                    const short8 ax = *(const short8*)(&xs[c15][pass][32 * kf + 8 * kg]);
                    axp[0] = MFMA(ax, wih0f[kf][0], axp[0]);
                    axp[1] = MFMA(ax, wih0f[kf][1], axp[1]);
                }
#pragma unroll
            for (int n = 0; n < 2; ++n)
#pragma unroll
                for (int j = 0; j < 4; ++j)
                    xp[4 * kg + j][cb0 + 16 * n] = axp[n][j] + bias0[n];
        }
        __syncthreads();

        // ---- phase B(c) + D(c-1): both recurrences; hi/lo in alternating A-rows ----
        const bool doD = (c > 0);
        for (int r = 0; r < TT; ++r) {
            const int dcur = r & 1, dprv = dcur ^ 1;
            const int ccol = 32 * wid + (lane & 31);
            // one addend read per lane: xp for layer-0 lanes, uch for layer-1
            const float* ap = (lane < 32) ? &xp[r][ccol] : &uch[r][ccol];
            const float addend = *ap;

            const ushort* h0p = &h0f[r * HR + mlow * HP + 8 * kg];
            const ushort* h1p = &h1f[dprv * HR + mlow * HP + 8 * kg];
            f32x4 a0[2], a1[2] = {vz, vz};
            {   // kf = 0: C = hoisted zero
                const short8 ah0 = *(const short8*)(h0p);
                a0[0] = mfma_az(ah0, whh0a[0][0], vz);
                a0[1] = mfma_az(ah0, whh0a[0][1], vz);
                if (doD) {
                    const short8 ah1 = *(const short8*)(h1p);
                    a1[0] = mfma_az(ah1, whh1a[0][0], vz);
                    a1[1] = mfma_az(ah1, whh1a[0][1], vz);
                }
            }
#pragma unroll
            for (int kf = 1; kf < 8; ++kf) {
                const short8 ah0 = *(const short8*)(h0p + 32 * kf);
                mfma_a(a0[0], ah0, whh0a[kf][0]);
                mfma_a(a0[1], ah0, whh0a[kf][1]);
                if (doD) {
                    const short8 ah1 = *(const short8*)(h1p + 32 * kf);
                    mfma_a(a1[0], ah1, whh1a[kf][0]);
                    mfma_a(a1[1], ah1, whh1a[kf][1]);
                }
            }
            // all-64-lane tail; ALL register-array indices compile-time
            // (rule #20), quadrant select done on VALUES via cndmask.
            {
                const int qn = (lane >> 4) & 1;          // n-tile quadrant
                const float s00 = a0[0][0] + a0[0][1];   // layer0, n=0
                const float s01 = a0[1][0] + a0[1][1];   // layer0, n=1
                const float s10 = a1[0][0] + a1[0][1];   // layer1, n=0
                const float s11 = a1[1][0] + a1[1][1];   // layer1, n=1
                const float s0 = qn ? s01 : s00;
                const float s1 = qn ? s11 : s10;
                const float h  = tanh_fast(((lane < 32) ? s0 : s1) + addend);
                const ushort hi = (ushort)bf16r(h);
                const ushort lo = (ushort)bf16r(h - bf2f(hi));
                ushort* dst = (lane < 32) ? &h0f[(r + 1) * HR] : &h1f[dcur * HR];
                if (doD || lane < 32) {
                    dst[ccol]      = hi;
                    dst[HP + ccol] = lo;
                }
            }
            __syncthreads();
        }

        // ---- phase C: u(c) = h0 @ Wih1^T + bias1 (M=16 timesteps, 2-pass);
        //      Wih1 streamed 2 frags/kf (low transient pressure) ----
        {
            f32x4 au[2] = {vz, vz};
#pragma unroll
            for (int kf = 0; kf < 8; ++kf) {
                const short8 w0 = ldfrag(Wih1 + (size_t)cb0 * HH + 32 * kf + 8 * kg);
                const short8 w1 = ldfrag(Wih1 + (size_t)(cb0 + 16) * HH + 32 * kf + 8 * kg);
#pragma unroll
                for (int pass = 0; pass < 2; ++pass) {
                    const short8 a = *(const short8*)(
                        &h0f[(1 + c15) * HR + pass * HP + 32 * kf + 8 * kg]);
                    au[0] = MFMA(a, w0, au[0]);
                    au[1] = MFMA(a, w1, au[1]);
                }
            }
#pragma unroll
            for (int n = 0; n < 2; ++n)
#pragma unroll
                for (int j = 0; j < 4; ++j)
                    uch[4 * kg + j][cb0 + 16 * n] = au[n][j] + bias1[n];
            // carry h0 row 16 -> row 0 (row 0 disjoint from phase-C rows 1..16)
            for (int i = tid; i < HR; i += 512) h0f[i] = h0f[TT * HR + i];
        }
        __syncthreads();
    }

    // ---- drain: layer-1 recurrence for the last chunk ----
    for (int r = 0; r < TT; ++r) {
        const int dcur = r & 1, dprv = dcur ^ 1;
        const int ccol = 32 * wid + (lane & 31);
        const float uvv = uch[r][ccol];
        const ushort* h1p = &h1f[dprv * HR + mlow * HP + 8 * kg];
        f32x4 a1[2];
        {
            const short8 ah1 = *(const short8*)(h1p);
            a1[0] = mfma_az(ah1, whh1a[0][0], vz);
            a1[1] = mfma_az(ah1, whh1a[0][1], vz);
        }
#pragma unroll
        for (int kf = 1; kf < 8; ++kf) {
            const short8 ah1 = *(const short8*)(h1p + 32 * kf);
            mfma_a(a1[0], ah1, whh1a[kf][0]);
            mfma_a(a1[1], ah1, whh1a[kf][1]);
        }
        {
            const int qn = (lane >> 4) & 1;
            const float s10 = a1[0][0] + a1[0][1];
            const float s11 = a1[1][0] + a1[1][1];
            const float h = tanh_fast((qn ? s11 : s10) + uvv);
            const ushort hi = (ushort)bf16r(h);
            const ushort lo = (ushort)bf16r(h - bf2f(hi));
            if (lane >= 32) {           // quadrants 2-3 own the h1 write
                h1f[dcur * HR + ccol]      = hi;
                h1f[dcur * HR + HP + ccol] = lo;
            }
        }
        __syncthreads();
    }

    // ---- FC + sigmoid on final h1 (r=15 -> parity 1), hi+lo recombined ----
    if (wid == 0) {
        float p = 0.f;
#pragma unroll
        for (int i = 0; i < 4; ++i) {
            const int ii = 4 * lane + i;
            p += (bf2f(h1f[HR + ii]) + bf2f(h1f[HR + HP + ii])) * Wfc[ii];
        }
#pragma unroll
        for (int off = 32; off > 0; off >>= 1) p += __shfl_down(p, off);
        if (lane == 0) {
            const float z = p + bfc[0];
            out[b] = 1.f / (1.f + expf(-z));
        }
    }
}

extern "C" void kernel_launch(void* const* d_in, const int* in_sizes, int n_in,
                              void* d_out, int out_size, void* d_ws, size_t ws_size,
                              hipStream_t stream) {
    (void)in_sizes; (void)n_in; (void)d_ws; (void)ws_size; (void)out_size;
    const float* x    = (const float*)d_in[0];
    const float* Wih0 = (const float*)d_in[1];
    const float* Whh0 = (const float*)d_in[2];
    const float* bih0 = (const float*)d_in[3];
    const float* bhh0 = (const float*)d_in[4];
    const float* Wih1 = (const float*)d_in[5];
    const float* Whh1 = (const float*)d_in[6];
    const float* bih1 = (const float*)d_in[7];
    const float* bhh1 = (const float*)d_in[8];
    const float* Wfc  = (const float*)d_in[9];
    const float* bfc  = (const float*)d_in[10];
    float* out = (float*)d_out;

    rnn_fused_kernel<<<dim3(BB), dim3(512), 0, stream>>>(
        x, Wih0, Whh0, bih0, bhh0, Wih1, Whh1, bih1, bhh1, Wfc, bfc, out);
}